// Round 1
// 8913.444 us; speedup vs baseline: 1.0103x; 1.0103x over previous
//
#include <hip/hip_runtime.h>

// GRU rollout: 257 sequential steps. v4: relaxed-poll barrier.
// v3 structure (LDS-resident weights, 256 blocks x 256 thr, fused x+h MFMA
// tiles, K-reduce into wave 0, 2-level device barrier) unchanged.
// v4 change: the gen-flag spin previously used an AGENT-scope ACQUIRE load
// per poll iteration -> hipcc emits buffer_inv sc1 (full XCD L2 invalidate)
// on EVERY poll. 32 blocks/XCD polling every ~200 cyc wiped L2 continuously,
// destroying XA/Hbuf intra-XCD sharing mid-step. Now: RELAXED poll +
// ONE acquire fence after the flag is observed (fence-after-relaxed-
// observation pattern; semantically equivalent, 1 inv per block per step).
//
// ws: Wc fp16 [6144][3072] | XA fp16 [257][64][1024] | Hbuf fp16 [2][64][2048]
//     rpart f32 [2][64][256] | bar u32[1024]

#define HT    2048
#define INW   1024
#define KTOT  3072
#define G3    6144
#define BB    64
#define TRR   256
#define NSTEP 257
#define NBLK  256
#define NTHR  256

#define LDS_STRIDE 6160                    // 6144 + 16 pad (banks: row*1540 %32 = 4*row)
#define LDS_W_BYTES (24 * LDS_STRIDE)      // 147840
#define LDS_SCRATCH 12288                  // 12 v4f x 64 lanes x 4 B
#define LDS_TOTAL (LDS_W_BYTES + LDS_SCRATCH)  // 160128 <= 163840

typedef _Float16 f16;
typedef _Float16 half8 __attribute__((ext_vector_type(8)));
typedef _Float16 half4x __attribute__((ext_vector_type(4)));
typedef float v4f __attribute__((ext_vector_type(4)));

__device__ __forceinline__ float sigm_(float x) {
  x = fminf(fmaxf(x, -30.f), 30.f);
  return 1.f / (1.f + __expf(-x));
}
__device__ __forceinline__ float tanh_(float x) {
  x = fminf(fmaxf(x, -15.f), 15.f);
  float e = __expf(2.f * x);
  return (e - 1.f) / (e + 1.f);
}

__global__ void prep_weights(const float* __restrict__ Wih, const float* __restrict__ Whh,
                             f16* __restrict__ Wc) {
  long idx = (long)blockIdx.x * blockDim.x + threadIdx.x;
  const long total = (long)G3 * KTOT / 4;
  if (idx >= total) return;
  long e = idx * 4;
  int j = (int)(e / KTOT);
  int k = (int)(e % KTOT);
  float4 v;
  if (k < INW) v = *(const float4*)(Wih + (long)j * INW + k);
  else         v = *(const float4*)(Whh + (long)j * HT + (k - INW));
  half4x h = { (f16)v.x, (f16)v.y, (f16)v.z, (f16)v.w };
  *(half4x*)(Wc + e) = h;
}

__global__ void prep_inputs(const float* __restrict__ ha, const float* __restrict__ a,
                            const float* __restrict__ hs,
                            f16* __restrict__ XA, f16* __restrict__ H0,
                            unsigned* __restrict__ bar) {
  long idx = (long)blockIdx.x * blockDim.x + threadIdx.x;
  const long nxa = (long)NSTEP * BB * INW / 4;   // 4,210,688
  const long nh  = (long)BB * HT / 4;            // 32,768
  if (idx < nxa) {
    long e = idx * 4;
    int t = (int)(e >> 16);
    int rem = (int)(e & 65535);
    int b = rem >> 10;
    int k = rem & 1023;
    const float* src = (t == 0) ? (ha + ((long)b * TRR + 255) * INW + k)
                                : (a  + ((long)b * TRR + (t - 1)) * INW + k);
    float4 v = *(const float4*)src;
    half4x h = { (f16)v.x, (f16)v.y, (f16)v.z, (f16)v.w };
    *(half4x*)(XA + e) = h;
  } else if (idx < nxa + nh) {
    long e = (idx - nxa) * 4;
    int b = (int)(e >> 11);
    int i = (int)(e & 2047);
    float4 v = *(const float4*)(hs + ((long)b * TRR + 255) * HT + i);
    half4x h = { (f16)v.x, (f16)v.y, (f16)v.z, (f16)v.w };
    *(half4x*)(H0 + e) = h;
  } else if (idx < nxa + nh + 1024) {
    bar[idx - (nxa + nh)] = 0u;                  // counters + root + gen
  }
}

// bar layout (uint indices): cnt[g] at g*32 (g=0..7), root at 256, gen at 288.
#define BAR_ROOT 256
#define BAR_GEN  288

__global__ void __launch_bounds__(NTHR)
gru_persist(const f16* __restrict__ Wc, const f16* __restrict__ XA,
            f16* __restrict__ Hbuf, float* __restrict__ rpart,
            unsigned* __restrict__ bar,
            const float* __restrict__ bih, const float* __restrict__ bhh,
            const float* __restrict__ Wr, const float* __restrict__ brp,
            float* __restrict__ out) {
  extern __shared__ char smem[];
  const int bid = blockIdx.x;          // channel group: c in [bid*8, bid*8+8)
  const int c0  = bid * 8;
  const int tid = threadIdx.x;
  const int w   = tid >> 6;            // wave id = K-quarter
  const int l   = tid & 63;
  const int q   = l >> 4;              // quad -> k sub-offset q*8
  const int ci  = l & 15;              // B-tile column

  // ---- stage 24 weight rows into LDS (once) ----
  // LDS row u: u<8 -> r rows, 8..15 -> z, 16..23 -> n ; global row j = g*HT + c0 + ch
  for (int cch = tid; cch < 24 * 384; cch += NTHR) {   // 16B chunks
    int u = cch / 384, off = (cch % 384) * 16;
    int g = u >> 3, ch = u & 7;
    long j = (long)g * HT + c0 + ch;
    *(float4*)(smem + (long)u * LDS_STRIDE + off) =
        *(const float4*)((const char*)Wc + j * (KTOT * 2) + off);
  }
  __syncthreads();

  // per-lane B-frag LDS bases
  const char* bT0 = smem + (long)ci * LDS_STRIDE + q * 16;                       // [r|z]
  const char* bT1 = smem + (long)(ci < 8 ? 16 + ci : ci - 8) * LDS_STRIDE + q * 16; // [n|dup]
  float* scr = (float*)(smem + LDS_W_BYTES);

  // gate constants for wave 0 lanes ci<8 (channel c = c0 + ci)
  const int c = c0 + (ci & 7);
  const float bi_r = bih[c],          bh_r = bhh[c];
  const float bi_z = bih[HT + c],     bh_z = bhh[HT + c];
  const float bi_n = bih[2 * HT + c], bh_n = bhh[2 * HT + c];
  const float wr = Wr[c];
  const float br = brp[0];
  float* outr = out;                        // [64][256]
  float* outs = out + (long)BB * TRR;       // [64][256][2048]

  for (int t = 0; t <= 256; ++t) {
    const f16* Xt  = XA + (long)t * BB * INW;
    const f16* Hin = Hbuf + (long)(t & 1) * BB * HT;
    f16* Hout      = Hbuf + (long)((t + 1) & 1) * BB * HT;

    v4f acc[12];                            // [0..3]=T0(rt), [4..7]=T1x, [8..11]=T1h
    #pragma unroll
    for (int i = 0; i < 12; ++i) acc[i] = (v4f){0.f, 0.f, 0.f, 0.f};

    // ---- x-side K-iters (pre-barrier: XA immutable, weights in LDS) ----
    #pragma unroll 4
    for (int j = 0; j < 8; ++j) {
      int k = w * 256 + j * 32;             // 0..1023
      half8 b0 = *(const half8*)(bT0 + (long)k * 2);
      half8 b1 = *(const half8*)(bT1 + (long)k * 2);
      #pragma unroll
      for (int rt = 0; rt < 4; ++rt) {
        half8 a = *(const half8*)(Xt + (long)(rt * 16 + ci) * INW + k + q * 8);
        acc[rt]     = __builtin_amdgcn_mfma_f32_16x16x32_f16(a, b0, acc[rt], 0, 0, 0);
        acc[4 + rt] = __builtin_amdgcn_mfma_f32_16x16x32_f16(a, b1, acc[4 + rt], 0, 0, 0);
      }
    }

    // ---- wait for h_{t-1} ----
    // v4: RELAXED poll (no per-iteration buffer_inv), single acquire fence
    // after observation. The old ACQUIRE-per-poll invalidated the XCD L2
    // every ~200 cycles from 32 blocks/XCD simultaneously.
    if (t > 0) {
      if (tid == 0) {
        while (__hip_atomic_load(&bar[BAR_GEN], __ATOMIC_RELAXED,
                                 __HIP_MEMORY_SCOPE_AGENT) < (unsigned)t)
          __builtin_amdgcn_s_sleep(4);
        __builtin_amdgcn_fence(__ATOMIC_ACQUIRE, "agent");
      }
      __syncthreads();   // S1
    }

    // ---- h-side K-iters ----
    #pragma unroll 4
    for (int j = 0; j < 16; ++j) {
      int kl = w * 512 + j * 32;            // 0..2047
      half8 b0 = *(const half8*)(bT0 + (long)(INW + kl) * 2);
      half8 b1 = *(const half8*)(bT1 + (long)(INW + kl) * 2);
      #pragma unroll
      for (int rt = 0; rt < 4; ++rt) {
        half8 a = *(const half8*)(Hin + (long)(rt * 16 + ci) * HT + kl + q * 8);
        acc[rt]     = __builtin_amdgcn_mfma_f32_16x16x32_f16(a, b0, acc[rt], 0, 0, 0);
        acc[8 + rt] = __builtin_amdgcn_mfma_f32_16x16x32_f16(a, b1, acc[8 + rt], 0, 0, 0);
      }
    }
    __syncthreads();     // S2

    // ---- K-reduce waves 1..3 into wave 0 (12 KB scratch, 3 rounds) ----
    for (int s = 1; s <= 3; ++s) {
      if (w == s) {
        #pragma unroll
        for (int v = 0; v < 12; ++v) *(v4f*)(scr + (v * 64 + l) * 4) = acc[v];
      }
      __syncthreads();
      if (w == 0) {
        #pragma unroll
        for (int v = 0; v < 12; ++v) acc[v] += *(const v4f*)(scr + (v * 64 + l) * 4);
      } else if (s == 1 && w == 1 && bid < BB && t >= 2) {
        // finalize reward for step t-2 (row = bid), off critical path
        const float* rp = rpart + (long)((t - 1) & 1) * BB * NBLK + (long)bid * NBLK;
        float v = rp[l] + rp[l + 64] + rp[l + 128] + rp[l + 192];
        v += __shfl_xor(v, 32, 64); v += __shfl_xor(v, 16, 64);
        v += __shfl_xor(v, 8, 64);  v += __shfl_xor(v, 4, 64);
        v += __shfl_xor(v, 2, 64);  v += __shfl_xor(v, 1, 64);
        if (l == 0) outr[(long)bid * TRR + (t - 2)] = sigm_(v + br);
      }
      __syncthreads();
    }

    // ---- gates (wave 0): C/D row = rt*16 + q*4 + rr, T0 col ci: r(ci<8)|z(ci-8) ----
    if (w == 0) {
      #pragma unroll
      for (int rt = 0; rt < 4; ++rt) {
        float zl[4];
        #pragma unroll
        for (int rr = 0; rr < 4; ++rr) zl[rr] = __shfl_xor(acc[rt][rr], 8, 16);
        if (ci < 8) {
          #pragma unroll
          for (int rr = 0; rr < 4; ++rr) {
            const int row = rt * 16 + q * 4 + rr;
            float rg = sigm_(acc[rt][rr] + bi_r + bh_r);
            float zg = sigm_(zl[rr] + bi_z + bh_z);
            float ng = tanh_(acc[4 + rt][rr] + bi_n + rg * (acc[8 + rt][rr] + bh_n));
            float hp = (float)Hin[(long)row * HT + c];
            float hn = (1.f - zg) * ng + zg * hp;
            Hout[(long)row * HT + c] = (f16)hn;
            if (t >= 1)
              __builtin_nontemporal_store(hn, outs + ((long)row * TRR + (t - 1)) * HT + c);
            float v = hn * wr;
            v += __shfl_xor(v, 1, 8); v += __shfl_xor(v, 2, 8); v += __shfl_xor(v, 4, 8);
            if (ci == 0)
              rpart[(long)(t & 1) * BB * NBLK + (long)row * NBLK + bid] = v;
          }
        }
      }
    }

    // ---- arrive (2-level: 8 per-XCD counters + root; monotone, masked) ----
    __syncthreads();     // drains all waves' stores before release
    if (tid == 0) {
      int g = bid & 7;
      unsigned p = __hip_atomic_fetch_add(&bar[g * 32], 1u, __ATOMIC_ACQ_REL,
                                          __HIP_MEMORY_SCOPE_AGENT);
      if ((p & 31) == 31) {
        unsigned pr = __hip_atomic_fetch_add(&bar[BAR_ROOT], 1u, __ATOMIC_ACQ_REL,
                                             __HIP_MEMORY_SCOPE_AGENT);
        if ((pr & 7) == 7)
          __hip_atomic_store(&bar[BAR_GEN], (unsigned)(t + 1), __ATOMIC_RELEASE,
                             __HIP_MEMORY_SCOPE_AGENT);
      }
    }
  }

  // ---- final reward column (t=256 -> r_list[:,255], parity 0) ----
  if (tid == 0) {
    while (__hip_atomic_load(&bar[BAR_GEN], __ATOMIC_RELAXED,
                             __HIP_MEMORY_SCOPE_AGENT) < 257u)
      __builtin_amdgcn_s_sleep(4);
    __builtin_amdgcn_fence(__ATOMIC_ACQUIRE, "agent");
  }
  __syncthreads();
  if (w == 1 && bid < BB) {
    const float* rp = rpart + (long)bid * NBLK;   // parity (256)&1 = 0
    float v = rp[l] + rp[l + 64] + rp[l + 128] + rp[l + 192];
    v += __shfl_xor(v, 32, 64); v += __shfl_xor(v, 16, 64);
    v += __shfl_xor(v, 8, 64);  v += __shfl_xor(v, 4, 64);
    v += __shfl_xor(v, 2, 64);  v += __shfl_xor(v, 1, 64);
    if (l == 0) outr[(long)bid * TRR + 255] = sigm_(v + br);
  }
}

extern "C" void kernel_launch(void* const* d_in, const int* in_sizes, int n_in,
                              void* d_out, int out_size, void* d_ws, size_t ws_size,
                              hipStream_t stream) {
  const float* hs  = (const float*)d_in[0];
  const float* ha  = (const float*)d_in[1];
  /* d_in[2] = s — unused by the reference */
  const float* a   = (const float*)d_in[3];
  const float* Wih = (const float*)d_in[4];
  const float* Whh = (const float*)d_in[5];
  const float* bih = (const float*)d_in[6];
  const float* bhh = (const float*)d_in[7];
  const float* Wr  = (const float*)d_in[8];
  const float* br  = (const float*)d_in[9];
  float* out = (float*)d_out;

  char* ws = (char*)d_ws;
  const size_t oWc  = 0;
  const size_t oXA  = oWc + (size_t)G3 * KTOT * 2;           // 37,748,736
  const size_t oHb  = oXA + (size_t)NSTEP * BB * INW * 2;    // +33,685,504
  const size_t oRp  = oHb + (size_t)2 * BB * HT * 2;         // +524,288
  const size_t oBar = oRp + (size_t)2 * BB * NBLK * 4;       // +131,072
  f16* Wc   = (f16*)(ws + oWc);
  f16* XA   = (f16*)(ws + oXA);
  f16* Hb   = (f16*)(ws + oHb);
  float* rp = (float*)(ws + oRp);
  unsigned* bar = (unsigned*)(ws + oBar);

  (void)hipFuncSetAttribute(reinterpret_cast<const void*>(gru_persist),
                            hipFuncAttributeMaxDynamicSharedMemorySize, LDS_TOTAL);

  {
    long quads = (long)G3 * KTOT / 4;
    prep_weights<<<dim3((unsigned)((quads + 255) / 256)), dim3(256), 0, stream>>>(Wih, Whh, Wc);
  }
  {
    long ntot = (long)NSTEP * BB * INW / 4 + (long)BB * HT / 4 + 1024;
    prep_inputs<<<dim3((unsigned)((ntot + 255) / 256)), dim3(256), 0, stream>>>(ha, a, hs, XA, Hb, bar);
  }
  {
    void* args[] = { &Wc, &XA, &Hb, &rp, &bar,
                     (void*)&bih, (void*)&bhh, (void*)&Wr, (void*)&br, &out };
    hipLaunchCooperativeKernel(reinterpret_cast<void*>(gru_persist),
                               dim3(NBLK), dim3(NTHR), args, LDS_TOTAL, stream);
  }
}